// Round 14
// baseline (153.284 us; speedup 1.0000x reference)
//
#include <hip/hip_runtime.h>
#include <math.h>
#include <limits.h>

#define NB 16
#define NC 21
#define NANCH 65536
#define NM 20

#define POS_THR 0.5f
#define NEG_THR 0.4f
#define F_ALPHA 0.25f
#define MIN_POS_TOPK 10
#define NEG_POS_RATIO 3

#define SBINS 256       // score bins: (unsigned)(s*256.0f), exact & monotone
#define QBINS 1024      // iou bins:   (unsigned)(q*1024.0f), exact & monotone
#define QCAP  8192      // global candidate list cap (top-10 path)
#define EQCAP 4096      // global boundary-bucket list cap
#define APT 2
#define IOU_TPB 256
#define ZWORDS (NB * QBINS + NB * SBINS + 4 * NB)   // qhist + shist + 4 counter arrays

__device__ __forceinline__ unsigned score_bin(float s) {
  unsigned b = (unsigned)(s * 256.0f);
  return b > (SBINS - 1) ? (SBINS - 1) : b;
}
__device__ __forceinline__ unsigned q_bin(float q) {
  unsigned b = (unsigned)(q * 1024.0f);
  return b > (QBINS - 1) ? (QBINS - 1) : b;
}

// ---------- K1: pure decode + IoU max/argmax; first 81 blocks also zero hists ----------
__global__ __launch_bounds__(IOU_TPB)
void k_iou(const float* __restrict__ reg, const float* __restrict__ anchors,
           const float* __restrict__ tb,
           float* __restrict__ miou, int* __restrict__ midx,
           unsigned* __restrict__ zbase) {
  // fold-in: zero the hist/counter region used by later kernels
  {
    int zi = blockIdx.x * IOU_TPB + threadIdx.x;
    if (zi < ZWORDS) zbase[zi] = 0u;
  }
  __shared__ float4 tbs4[NM];
  __shared__ float  tarea[NM];
  int b   = blockIdx.x >> 7;           // 128 blocks per image
  int blk = blockIdx.x & 127;
  int n0  = (blk << 9) + threadIdx.x;  // 512 anchors per block
  if (threadIdx.x < NM) {
    float4 t4 = ((const float4*)tb)[b * NM + threadIdx.x];
    tbs4[threadIdx.x] = t4;
    tarea[threadIdx.x] = (t4.z - t4.x) * (t4.w - t4.y);
  }
  __syncthreads();

  float dv[APT][4];
  float areaA[APT];
  #pragma unroll
  for (int j = 0; j < APT; ++j) {
    int n = n0 + j * IOU_TPB;
    float4 a4 = ((const float4*)anchors)[n];
    float aw = a4.z - a4.x, ah = a4.w - a4.y;
    float acx = a4.x + 0.5f * aw, acy = a4.y + 0.5f * ah;
    size_t rb = ((size_t)b * 4) * NANCH + n;
    float rx = reg[rb];
    float ry = reg[rb + (size_t)NANCH];
    float rw = reg[rb + 2 * (size_t)NANCH];
    float rh = reg[rb + 3 * (size_t)NANCH];
    float cx = acx + rx * aw, cy = acy + ry * ah;
    float w = aw * expf(rw), h = ah * expf(rh);
    dv[j][0] = cx - 0.5f * w;
    dv[j][1] = cy - 0.5f * h;
    dv[j][2] = cx + 0.5f * w;
    dv[j][3] = cy + 0.5f * h;
    areaA[j] = (dv[j][2] - dv[j][0]) * (dv[j][3] - dv[j][1]);
  }

  float bI[APT], bU[APT];
  int   bM[APT];
  {
    float4 t = tbs4[0];
    float ab = tarea[0];
    #pragma unroll
    for (int j = 0; j < APT; ++j) {
      float lx = fmaxf(dv[j][0], t.x), ly = fmaxf(dv[j][1], t.y);
      float rx2 = fminf(dv[j][2], t.z), ry2 = fminf(dv[j][3], t.w);
      float iw = fmaxf(rx2 - lx, 0.0f), ih = fmaxf(ry2 - ly, 0.0f);
      float inter = iw * ih;
      bI[j] = inter;
      bU[j] = areaA[j] + ab - inter;
      bM[j] = 0;
    }
  }
  #pragma unroll
  for (int m = 1; m < NM; ++m) {
    float4 t = tbs4[m];
    float ab = tarea[m];
    #pragma unroll
    for (int j = 0; j < APT; ++j) {
      float lx = fmaxf(dv[j][0], t.x), ly = fmaxf(dv[j][1], t.y);
      float rx2 = fminf(dv[j][2], t.z), ry2 = fminf(dv[j][3], t.w);
      float iw = fmaxf(rx2 - lx, 0.0f), ih = fmaxf(ry2 - ly, 0.0f);
      float inter = iw * ih;
      float uni = areaA[j] + ab - inter;
      // inter/uni > bI/bU  <=>  inter*bU > bI*uni (both unions > 0)
      if (inter * bU[j] > bI[j] * uni) { bI[j] = inter; bU[j] = uni; bM[j] = m; }
    }
  }

  #pragma unroll
  for (int j = 0; j < APT; ++j) {
    int n = n0 + j * IOU_TPB;
    size_t idx = (size_t)b * NANCH + n;
    miou[idx] = bI[j] / fmaxf(bU[j], 1e-7f);   // IEEE, matches reference
    midx[idx] = bM[j];
  }
}

// ---------- K2: parallel histogram build (LDS + flush) ----------
__global__ __launch_bounds__(1024)
void k_hist(const float* __restrict__ miou, const float* __restrict__ scores,
            unsigned* __restrict__ qhist, unsigned* __restrict__ shist,
            int* __restrict__ pos_cnt, int* __restrict__ neg_cnt) {
  __shared__ unsigned lqh[QBINS];
  __shared__ unsigned lsh[SBINS];
  int b   = blockIdx.x >> 4;        // 16 blocks per image
  int seg = blockIdx.x & 15;        // 4096 anchors per block
  const float* mi = miou + (size_t)b * NANCH;
  const float* sc = scores + (size_t)b * NANCH;
  for (int j = threadIdx.x; j < QBINS; j += 1024) lqh[j] = 0u;
  if (threadIdx.x < SBINS) lsh[threadIdx.x] = 0u;
  __syncthreads();
  int lane = threadIdx.x & 63;
  int cp = 0, cn = 0;
  int base = seg * 4096;
  #pragma unroll
  for (int i = 0; i < 4; ++i) {
    int n = base + i * 1024 + threadIdx.x;
    float q = mi[n];
    bool p  = (q >= POS_THR);
    bool ng = (q < NEG_THR);
    cp += p ? 1 : 0;
    cn += ng ? 1 : 0;
    // batch exact-zero mass per wave (bin 0 is the heavy tie bin)
    unsigned long long zm = __ballot(q == 0.0f);
    if (q != 0.0f) atomicAdd(&lqh[q_bin(q)], 1u);
    else if (lane == __ffsll(zm) - 1) atomicAdd(&lqh[0], (unsigned)__popcll(zm));
    if (ng) atomicAdd(&lsh[score_bin(sc[n])], 1u);
  }
  #pragma unroll
  for (int m = 32; m >= 1; m >>= 1) {
    cp += __shfl_down(cp, m, 64);
    cn += __shfl_down(cn, m, 64);
  }
  if (lane == 0) {
    if (cp) atomicAdd(&pos_cnt[b], cp);
    if (cn) atomicAdd(&neg_cnt[b], cn);
  }
  __syncthreads();
  for (int j = threadIdx.x; j < QBINS; j += 1024) {
    unsigned c = lqh[j];
    if (c) atomicAdd(&qhist[b * QBINS + j], c);
  }
  if (threadIdx.x < SBINS) {
    unsigned c = lsh[threadIdx.x];
    if (c) atomicAdd(&shist[b * SBINS + threadIdx.x], c);
  }
}

// ---------- K3: parallel threshold scans (suffix for qtb, prefix for s-bucket) ----------
__global__ __launch_bounds__(1024)
void k_thresh(const unsigned* __restrict__ qhist, const unsigned* __restrict__ shist,
              const int* __restrict__ pos_cnt, const int* __restrict__ neg_cnt,
              int* __restrict__ num_pos, int* __restrict__ use_fb,
              int* __restrict__ subsample, int* __restrict__ total_samples,
              int* __restrict__ qtb, int* __restrict__ bucket, int* __restrict__ below,
              unsigned* __restrict__ vbits_out, int* __restrict__ idx_cut,
              float* __restrict__ sums) {
  int b = blockIdx.x;
  __shared__ unsigned sA[QBINS];
  __shared__ unsigned sB[QBINS];
  __shared__ int sh_k, sh_sub;
  int t = threadIdx.x;
  sA[t] = qhist[b * QBINS + t];
  unsigned hs_orig = 0;
  if (t < SBINS) hs_orig = shist[b * SBINS + t];
  if (t == 0) {
    int pc = pos_cnt[b], nc = neg_cnt[b];
    int fb = (pc < MIN_POS_TOPK) ? 1 : 0;
    int np = fb ? MIN_POS_TOPK : pc;
    int k = NEG_POS_RATIO * np;
    int sub = (nc <= k) ? 0 : 1;
    sh_k = k; sh_sub = sub;
    num_pos[b] = np; use_fb[b] = fb; subsample[b] = sub;
    total_samples[b] = sub ? (np + k) : (np + nc);
    sums[b * 3 + 0] = 0.0f; sums[b * 3 + 1] = 0.0f; sums[b * 3 + 2] = 0.0f;
    if (!sub) { vbits_out[b] = 0u; idx_cut[b] = -1; }
  }
  __syncthreads();

  // suffix sum over q-hist (Hillis-Steele, ping-pong)
  unsigned* src = sA; unsigned* dst = sB;
  for (int d = 1; d < QBINS; d <<= 1) {
    unsigned v = src[t];
    if (t + d < QBINS) v += src[t + d];
    dst[t] = v;
    __syncthreads();
    unsigned* tmp = src; src = dst; dst = tmp;
  }
  unsigned sfx_t  = src[t];
  unsigned sfx_t1 = (t + 1 < QBINS) ? src[t + 1] : 0u;
  // sfx is non-increasing: unique boundary
  if (sfx_t >= (unsigned)MIN_POS_TOPK &&
      (t == QBINS - 1 || sfx_t1 < (unsigned)MIN_POS_TOPK)) qtb[b] = t;
  __syncthreads();

  // inclusive prefix over s-hist (only needed when subsampling)
  if (sh_sub) {
    if (t < SBINS) sA[t] = hs_orig;
    __syncthreads();
    unsigned* s1 = sA; unsigned* s2 = sB;
    for (int d = 1; d < SBINS; d <<= 1) {
      if (t < SBINS) {
        unsigned v = s1[t];
        if (t >= d) v += s1[t - d];
        s2[t] = v;
      }
      __syncthreads();
      unsigned* tm = s1; s1 = s2; s2 = tm;
    }
    if (t < SBINS) {
      unsigned incl = s1[t];
      unsigned inclp = (t == 0) ? 0u : s1[t - 1];
      if ((int)incl >= sh_k && (t == 0 || (int)inclp < sh_k)) {
        bucket[b] = t;
        below[b] = (int)(incl - hs_orig);
      }
    }
  }
}

// ---------- K4: wide gather into small global lists ----------
__global__ __launch_bounds__(1024)
void k_gather(const float* __restrict__ miou, const float* __restrict__ scores,
              const int* __restrict__ qtb, const int* __restrict__ subsample,
              const int* __restrict__ bucket,
              unsigned* __restrict__ qcb, int* __restrict__ qci, int* __restrict__ qcnt,
              unsigned* __restrict__ eqb, int* __restrict__ eqi, int* __restrict__ eqcnt) {
  int b = blockIdx.x >> 6;                       // 64 blocks per image
  int n = ((blockIdx.x & 63) << 10) | threadIdx.x;
  size_t idx = (size_t)b * NANCH + n;
  float q = miou[idx];
  if ((int)q_bin(q) >= qtb[b]) {
    int slot = atomicAdd(&qcnt[b], 1);
    if (slot < QCAP) {
      qcb[(size_t)b * QCAP + slot] = __float_as_uint(q);  // q >= 0: bit order == value order
      qci[(size_t)b * QCAP + slot] = n;
    }
  }
  if (q < NEG_THR && subsample[b]) {
    float s = scores[idx];
    if ((int)score_bin(s) == bucket[b]) {
      int slot = atomicAdd(&eqcnt[b], 1);
      if (slot < EQCAP) {
        eqb[(size_t)b * EQCAP + slot] = __float_as_uint(s);
        eqi[(size_t)b * EQCAP + slot] = n;
      }
    }
  }
}

// ---------- K5: blocks 0..15 exact top-10, 16..31 exact negative cut ----------
__global__ __launch_bounds__(256)
void k_sel(const unsigned* __restrict__ qcb, const int* __restrict__ qci,
           const int* __restrict__ qcnt,
           const unsigned* __restrict__ eqb, const int* __restrict__ eqi,
           const int* __restrict__ eqcnt,
           const int* __restrict__ subsample, const int* __restrict__ num_pos,
           const int* __restrict__ below,
           const float* __restrict__ miou,
           int* __restrict__ top10,
           unsigned* __restrict__ vbits_out, int* __restrict__ idx_cut) {
  __shared__ unsigned bB[4096];
  __shared__ int      bI[4096];
  __shared__ float fsv[256];
  __shared__ int   fsi[256];
  __shared__ int   fsel[MIN_POS_TOPK];
  if (blockIdx.x < NB) {
    int b = blockIdx.x;
    int E = qcnt[b];
    const unsigned* qb_ = qcb + (size_t)b * QCAP;
    const int*      qi_ = qci + (size_t)b * QCAP;
    if (E <= 4096) {
      for (int j = threadIdx.x; j < E; j += 256) { bB[j] = qb_[j]; bI[j] = qi_[j]; }
      __syncthreads();
      for (int e = threadIdx.x; e < E; e += 256) {
        unsigned mb = bB[e]; int mi_ = bI[e];
        int rank = 0;
        for (int j = 0; j < E; ++j) {
          unsigned ob = bB[j]; int oi = bI[j];
          rank += (ob > mb || (ob == mb && oi < mi_)) ? 1 : 0;
        }
        if (rank < MIN_POS_TOPK) top10[b * MIN_POS_TOPK + rank] = mi_;
      }
    } else if (E <= QCAP) {
      for (int e = threadIdx.x; e < E; e += 256) {
        unsigned mb = qb_[e]; int mi_ = qi_[e];
        int rank = 0;
        for (int j = 0; j < E; ++j) {
          unsigned ob = qb_[j]; int oi = qi_[j];
          rank += (ob > mb || (ob == mb && oi < mi_)) ? 1 : 0;
        }
        if (rank < MIN_POS_TOPK) top10[b * MIN_POS_TOPK + rank] = mi_;
      }
    } else {
      // fallback (structurally ~never): exact 10-iteration scan over miou
      const float* mi = miou + (size_t)b * NANCH;
      int lane = threadIdx.x & 63;
      int wid  = threadIdx.x >> 6;
      for (int it = 0; it < MIN_POS_TOPK; ++it) {
        float bv = -1.0f; int bi = NANCH;
        for (int n = threadIdx.x; n < NANCH; n += 256) {
          bool skip = false;
          for (int s2 = 0; s2 < it; ++s2) if (fsel[s2] == n) skip = true;
          if (skip) continue;
          float v = mi[n];
          if (v > bv || (v == bv && n < bi)) { bv = v; bi = n; }
        }
        #pragma unroll
        for (int m = 32; m >= 1; m >>= 1) {
          float ov = __shfl_xor(bv, m, 64);
          int   oi = __shfl_xor(bi, m, 64);
          if (ov > bv || (ov == bv && oi < bi)) { bv = ov; bi = oi; }
        }
        if (lane == 0) { fsv[wid] = bv; fsi[wid] = bi; }
        __syncthreads();
        if (threadIdx.x == 0) {
          float bb = -1.0f; int bj = NANCH;
          for (int w = 0; w < 4; ++w)
            if (fsv[w] > bb || (fsv[w] == bb && fsi[w] < bj)) { bb = fsv[w]; bj = fsi[w]; }
          fsel[it] = bj;
        }
        __syncthreads();
      }
      if (threadIdx.x < MIN_POS_TOPK) top10[b * MIN_POS_TOPK + threadIdx.x] = fsel[threadIdx.x];
    }
  } else {
    int b = blockIdx.x - NB;
    if (!subsample[b]) return;   // vbits/idx_cut already set by k_thresh
    int E = eqcnt[b]; if (E > EQCAP) E = EQCAP;
    int r = NEG_POS_RATIO * num_pos[b] - below[b];   // 1-based rank within bucket
    if (threadIdx.x == 0 && (r < 1 || r > E)) {      // overflow safety (never expected)
      vbits_out[b] = 0xFFFFFFFFu; idx_cut[b] = NANCH;
    }
    for (int j = threadIdx.x; j < E; j += 256) {
      bB[j] = eqb[(size_t)b * EQCAP + j];
      bI[j] = eqi[(size_t)b * EQCAP + j];
    }
    __syncthreads();
    for (int e = threadIdx.x; e < E; e += 256) {
      unsigned mb = bB[e]; int mi_ = bI[e];
      int rank = 0;
      for (int j = 0; j < E; ++j) {
        unsigned ob = bB[j]; int oi = bI[j];
        rank += (ob < mb || (ob == mb && oi < mi_)) ? 1 : 0;
      }
      if (rank == r - 1) { vbits_out[b] = mb; idx_cut[b] = mi_; }
    }
  }
}

// ---------- K6: per-anchor loss accumulation ----------
__global__ __launch_bounds__(256)
void k_loss(const float* __restrict__ cls, const float* __restrict__ reg,
            const float* __restrict__ anchors, const float* __restrict__ tb,
            const int* __restrict__ tl, const float* __restrict__ scores,
            const float* __restrict__ miou, const int* __restrict__ midx,
            const int* __restrict__ use_fb, const int* __restrict__ top10,
            const int* __restrict__ subsample, const unsigned* __restrict__ vbits,
            const int* __restrict__ idx_cut,
            float* __restrict__ sums /* [NB][3] : pos, neg, reg */) {
  int b = blockIdx.x >> 8;
  int n = ((blockIdx.x & 255) << 8) | threadIdx.x;
  __shared__ int s_top10[MIN_POS_TOPK];
  __shared__ int s_usefb, s_sub, s_cut;
  __shared__ unsigned s_vb;
  __shared__ float accp, accn, accr;
  if (threadIdx.x < MIN_POS_TOPK) s_top10[threadIdx.x] = top10[b * MIN_POS_TOPK + threadIdx.x];
  if (threadIdx.x == 0) {
    s_usefb = use_fb[b]; s_sub = subsample[b]; s_cut = idx_cut[b]; s_vb = vbits[b];
    accp = 0.0f; accn = 0.0f; accr = 0.0f;
  }
  __syncthreads();

  size_t idx = (size_t)b * NANCH + n;
  float mi = miou[idx];

  bool pos;
  if (s_usefb) {
    pos = false;
    #pragma unroll
    for (int i = 0; i < MIN_POS_TOPK; ++i) pos |= (s_top10[i] == n);
  } else {
    pos = (mi >= POS_THR);
  }
  bool neg = (mi < NEG_THR);
  bool nsel = false;
  if (neg) {
    if (!s_sub) nsel = true;
    else {
      unsigned sb = __float_as_uint(scores[idx]);
      nsel = (sb < s_vb) || (sb == s_vb && n <= s_cut);
    }
  }

  float cp = 0.0f, cn = 0.0f, rg = 0.0f;
  if (pos || nsel) {
    int mx = 0, t = 0;
    if (pos) { mx = midx[idx]; t = tl[b * NM + mx]; }
    size_t cb = ((size_t)b * NC) * NANCH + n;
    float mxl = -3.0e38f, l0 = 0.0f, lt = 0.0f;
    for (int c = 0; c < NC; ++c) {
      float l = cls[cb + (size_t)c * NANCH];
      if (c == 0) l0 = l;
      if (c == t) lt = l;
      mxl = fmaxf(mxl, l);
    }
    float se = 0.0f;
    for (int c = 0; c < NC; ++c) {
      float l = cls[cb + (size_t)c * NANCH];
      se += expf(l - mxl);
    }
    float lse = mxl + logf(se);
    if (nsel) {
      float ce = lse - l0;
      float pt = expf(-ce);
      float om = 1.0f - pt;
      cn = F_ALPHA * om * om * ce;
    }
    if (pos) {
      float ce = lse - lt;
      float pt = expf(-ce);
      float om = 1.0f - pt;
      cp = F_ALPHA * om * om * ce;
      // decode + GIoU vs matched GT
      const float4 a4 = ((const float4*)anchors)[n];
      float aw = a4.z - a4.x, ah = a4.w - a4.y;
      float acx = a4.x + 0.5f * aw, acy = a4.y + 0.5f * ah;
      size_t rb = ((size_t)b * 4) * NANCH + n;
      float rx = reg[rb];
      float ry = reg[rb + (size_t)NANCH];
      float rw = reg[rb + 2 * (size_t)NANCH];
      float rh = reg[rb + 3 * (size_t)NANCH];
      float ccx = acx + rx * aw, ccy = acy + ry * ah;
      float w = aw * expf(rw), h = ah * expf(rh);
      float d0 = ccx - 0.5f * w, d1 = ccy - 0.5f * h;
      float d2 = ccx + 0.5f * w, d3 = ccy + 0.5f * h;
      const float* g = tb + ((size_t)b * NM + mx) * 4;
      float gx1 = g[0], gy1 = g[1], gx2 = g[2], gy2 = g[3];
      float area_a = (d2 - d0) * (d3 - d1);
      float area_b = (gx2 - gx1) * (gy2 - gy1);
      float lx = fmaxf(d0, gx1), ly = fmaxf(d1, gy1);
      float rx2 = fminf(d2, gx2), ry2 = fminf(d3, gy2);
      float iw = fmaxf(rx2 - lx, 0.0f), ih = fmaxf(ry2 - ly, 0.0f);
      float inter = iw * ih;
      float uni = area_a + area_b - inter;
      float iou = inter / fmaxf(uni, 1e-7f);
      float ex1 = fminf(d0, gx1), ey1 = fminf(d1, gy1);
      float ex2 = fmaxf(d2, gx2), ey2 = fmaxf(d3, gy2);
      float ew = fmaxf(ex2 - ex1, 0.0f), eh = fmaxf(ey2 - ey1, 0.0f);
      float enc = ew * eh;
      float giou = iou - (enc - uni) / fmaxf(enc, 1e-7f);
      rg = 1.0f - giou;
    }
  }

  if (cp != 0.0f) atomicAdd(&accp, cp);
  if (cn != 0.0f) atomicAdd(&accn, cn);
  if (rg != 0.0f) atomicAdd(&accr, rg);
  __syncthreads();
  if (threadIdx.x == 0) {
    if (accp != 0.0f) atomicAdd(&sums[b * 3 + 0], accp);
    if (accn != 0.0f) atomicAdd(&sums[b * 3 + 1], accn);
    if (accr != 0.0f) atomicAdd(&sums[b * 3 + 2], accr);
  }
}

// ---------- K7: finalize (parallel, 64 threads) ----------
__global__ void k_final(const float* __restrict__ sums,
                        const int* __restrict__ total_samples,
                        const int* __restrict__ num_pos,
                        float* __restrict__ out) {
  int t = threadIdx.x;
  float cm = 0.0f, rm = 0.0f;
  if (t < NB) {
    int ts = total_samples[t]; if (ts < 1) ts = 1;
    int np = num_pos[t]; if (np < 1) np = 1;
    cm = (sums[t * 3 + 0] + sums[t * 3 + 1]) / (float)ts;
    rm = sums[t * 3 + 2] / (float)np;
  }
  #pragma unroll
  for (int m = 8; m >= 1; m >>= 1) {
    cm += __shfl_down(cm, m, 64);
    rm += __shfl_down(rm, m, 64);
  }
  if (t == 0) out[0] = cm / (float)NB + rm / (float)NB;
}

extern "C" void kernel_launch(void* const* d_in, const int* in_sizes, int n_in,
                              void* d_out, int out_size, void* d_ws, size_t ws_size,
                              hipStream_t stream) {
  const float* cls     = (const float*)d_in[0];
  const float* reg     = (const float*)d_in[1];
  const float* anchors = (const float*)d_in[2];
  const float* tb      = (const float*)d_in[3];
  const int*   tl      = (const int*)d_in[4];
  const float* scores  = (const float*)d_in[5];
  float* out = (float*)d_out;

  char* ws = (char*)d_ws;
  size_t off = 0;
  float* miou = (float*)(ws + off);            off += (size_t)4 * NB * NANCH;
  int*   midx = (int*)(ws + off);              off += (size_t)4 * NB * NANCH;
  // zero-region (contiguous; cleared by k_iou's fold-in)
  unsigned* zbase = (unsigned*)(ws + off);
  unsigned* qhist = zbase;                                    // NB*QBINS
  unsigned* shist = zbase + NB * QBINS;                       // NB*SBINS
  int* pos_cnt    = (int*)(zbase + NB * QBINS + NB * SBINS);
  int* neg_cnt    = pos_cnt + NB;
  int* qcnt       = pos_cnt + 2 * NB;
  int* eqcnt      = pos_cnt + 3 * NB;
  off += (size_t)4 * ZWORDS;
  unsigned* qcb = (unsigned*)(ws + off);       off += (size_t)4 * NB * QCAP;
  int*   qci = (int*)(ws + off);               off += (size_t)4 * NB * QCAP;
  unsigned* eqb = (unsigned*)(ws + off);       off += (size_t)4 * NB * EQCAP;
  int*   eqi = (int*)(ws + off);               off += (size_t)4 * NB * EQCAP;
  int* scal = (int*)(ws + off);
  int* num_pos       = scal;
  int* use_fb        = scal + NB;
  int* subsample     = scal + 2 * NB;
  int* idx_cut       = scal + 3 * NB;
  unsigned* vbits    = (unsigned*)(scal + 4 * NB);
  int* total_samples = scal + 5 * NB;
  int* qtb           = scal + 6 * NB;
  int* bucket        = scal + 7 * NB;
  int* below         = scal + 8 * NB;
  int* top10         = scal + 9 * NB;                          // NB*10
  float* sums        = (float*)(scal + 9 * NB + MIN_POS_TOPK * NB); // NB*3

  k_iou<<<NB * 128, IOU_TPB, 0, stream>>>(reg, anchors, tb, miou, midx, zbase);
  k_hist<<<NB * 16, 1024, 0, stream>>>(miou, scores, qhist, shist, pos_cnt, neg_cnt);
  k_thresh<<<NB, 1024, 0, stream>>>(qhist, shist, pos_cnt, neg_cnt,
                                    num_pos, use_fb, subsample, total_samples,
                                    qtb, bucket, below, vbits, idx_cut, sums);
  k_gather<<<NB * 64, 1024, 0, stream>>>(miou, scores, qtb, subsample, bucket,
                                         qcb, qci, qcnt, eqb, eqi, eqcnt);
  k_sel<<<2 * NB, 256, 0, stream>>>(qcb, qci, qcnt, eqb, eqi, eqcnt,
                                    subsample, num_pos, below, miou,
                                    top10, vbits, idx_cut);
  k_loss<<<NB * 256, 256, 0, stream>>>(cls, reg, anchors, tb, tl, scores,
                                       miou, midx, use_fb, top10, subsample,
                                       vbits, idx_cut, sums);
  k_final<<<1, 64, 0, stream>>>(sums, total_samples, num_pos, out);
}